// Round 1
// baseline (503.542 us; speedup 1.0000x reference)
//
#include <hip/hip_runtime.h>

// Shapes fixed by the reference: (B=8, C=8, H=1024, W=1024) fp32, two images.
constexpr int B = 8, C = 8;
constexpr long long PLANE = 1024LL * 1024LL;          // H*W floats per (b,c) plane
constexpr long long NCHW  = (long long)C * PLANE;     // 8,388,608 per-batch elements
constexpr int BLOCKS_PER_PLANE = 16;                  // 2*64 planes * 16 = 2048 blocks
constexpr int THREADS = 256;
constexpr int F4_PER_BLOCK = (int)(PLANE / BLOCKS_PER_PLANE / 4); // 16384 float4
constexpr int ITERS = F4_PER_BLOCK / THREADS;                      // 64

// acc layout: [img(2)][b(8)][4] doubles = {S1, S2, D1, D2}
__global__ __launch_bounds__(THREADS) void moments_pass1(
    const float* __restrict__ img0, const float* __restrict__ img1,
    double* __restrict__ acc) {
  int gb    = blockIdx.x;                 // 0..2047
  int plane = gb / BLOCKS_PER_PLANE;      // 0..127
  int chunk = gb % BLOCKS_PER_PLANE;      // 0..15
  int imgi  = plane >> 6;                 // 0,1
  int rem   = plane & 63;                 // b*8 + c
  int b     = rem >> 3;
  int c     = rem & 7;

  const float* base = (imgi ? img1 : img0)
                    + (long long)rem * PLANE
                    + (long long)chunk * (PLANE / BLOCKS_PER_PLANE);
  const float4* p = (const float4*)base;

  double s1 = 0.0, s2 = 0.0;
  int tid = threadIdx.x;
#pragma unroll 8
  for (int it = 0; it < ITERS; ++it) {
    float4 v = p[it * THREADS + tid];
    double a = (double)v.x, bb = (double)v.y, cc = (double)v.z, d = (double)v.w;
    s1 += (a + bb) + (cc + d);
    s2 = fma(a, a, s2); s2 = fma(bb, bb, s2);
    s2 = fma(cc, cc, s2); s2 = fma(d, d, s2);
  }

  // wave-64 shuffle tree
  for (int off = 32; off > 0; off >>= 1) {
    s1 += __shfl_down(s1, off, 64);
    s2 += __shfl_down(s2, off, 64);
  }

  __shared__ double sh1[4], sh2[4];
  int wave = tid >> 6, lane = tid & 63;
  if (lane == 0) { sh1[wave] = s1; sh2[wave] = s2; }
  __syncthreads();
  if (tid == 0) {
    double t1 = (sh1[0] + sh1[1]) + (sh1[2] + sh1[3]);
    double t2 = (sh2[0] + sh2[1]) + (sh2[2] + sh2[3]);
    double* a4 = acc + ((imgi * B + b) * 4);
    atomicAdd(&a4[0], t1);
    atomicAdd(&a4[1], t2);
    if (c == b) {  // diagonal plane feeds the moment numerator
      atomicAdd(&a4[2], t1);
      atomicAdd(&a4[3], t2);
    }
  }
}

__global__ void moments_pass2(const double* __restrict__ acc,
                              float* __restrict__ out) {
  if (blockIdx.x == 0 && threadIdx.x == 0) {
    const double N    = (double)NCHW;       // 8388608
    const double Npix = (double)PLANE;      // 1048576
    const double denom = N * N;             // (C*H*W)^ORDER, ORDER=2
    double res[2];
    for (int i = 0; i < 2; ++i) {
      double msum = 0.0;
      for (int m = 0; m < B; ++m) {
        const double* a = acc + (i * B + m) * 4;
        double S1 = a[0], S2 = a[1], D1 = a[2], D2 = a[3];
        double mean = S1 / N;
        double var  = (S2 - S1 * S1 / N) / (N - 1.0);  // unbiased (ddof=1)
        double ssq  = D2 - 2.0 * mean * D1 + Npix * mean * mean;
        msum += ssq / var / denom;
      }
      res[i] = msum;
    }
    out[0] = (float)fabs(res[0] - res[1]);
  }
}

extern "C" void kernel_launch(void* const* d_in, const int* in_sizes, int n_in,
                              void* d_out, int out_size, void* d_ws, size_t ws_size,
                              hipStream_t stream) {
  const float* img0 = (const float*)d_in[0];
  const float* img1 = (const float*)d_in[1];
  double* acc = (double*)d_ws;  // 64 doubles = 512 B, ws is re-poisoned -> zero it
  hipMemsetAsync(d_ws, 0, 2 * B * 4 * sizeof(double), stream);
  moments_pass1<<<2 * B * C * BLOCKS_PER_PLANE, THREADS, 0, stream>>>(img0, img1, acc);
  moments_pass2<<<1, 64, 0, stream>>>(acc, (float*)d_out);
}

// Round 2
// 467.614 us; speedup vs baseline: 1.0768x; 1.0768x over previous
//
#include <hip/hip_runtime.h>

// Shapes fixed by the reference: (B=8, C=8, H=1024, W=1024) fp32, two images.
constexpr int B = 8, C = 8;
constexpr long long PLANE = 1024LL * 1024LL;          // H*W floats per (b,c) plane
constexpr long long NCHW  = (long long)C * PLANE;     // 8,388,608 per-batch elements
constexpr int BLOCKS_PER_PLANE = 16;                  // 2*64 planes * 16 = 2048 blocks
constexpr int NBLOCKS = 2 * B * C * BLOCKS_PER_PLANE; // 2048
constexpr int THREADS = 256;
constexpr int F4_PER_BLOCK = (int)(PLANE / BLOCKS_PER_PLANE / 4); // 16384 float4
constexpr int ITERS = F4_PER_BLOCK / THREADS;                      // 64

typedef float f32x4 __attribute__((ext_vector_type(4)));

// Per-block partials: part[gb] = {sum(x), sum(x^2)} over the block's chunk.
// Every slot is written unconditionally -> no zero-init of d_ws needed.
__global__ __launch_bounds__(THREADS) void moments_pass1(
    const float* __restrict__ img0, const float* __restrict__ img1,
    double2* __restrict__ part) {
  int gb    = blockIdx.x;                 // 0..2047
  int plane = gb / BLOCKS_PER_PLANE;      // 0..127  (imgi*64 + b*8 + c)
  int chunk = gb % BLOCKS_PER_PLANE;      // 0..15
  int imgi  = plane >> 6;
  int rem   = plane & 63;

  const float* base = (imgi ? img1 : img0)
                    + (long long)rem * PLANE
                    + (long long)chunk * (PLANE / BLOCKS_PER_PLANE);
  const f32x4* p = (const f32x4*)base;

  int tid = threadIdx.x;
  double s1a = 0.0, s1b = 0.0;
  double q0 = 0.0, q1 = 0.0, q2 = 0.0, q3 = 0.0;
#pragma unroll 8
  for (int it = 0; it < ITERS; ++it) {
    f32x4 v = __builtin_nontemporal_load(p + it * THREADS + tid);
    double a = (double)v.x, b2 = (double)v.y, c2 = (double)v.z, d = (double)v.w;
    s1a += a + b2;
    s1b += c2 + d;
    q0 = fma(a, a, q0);
    q1 = fma(b2, b2, q1);
    q2 = fma(c2, c2, q2);
    q3 = fma(d, d, q3);
  }
  double s1 = s1a + s1b;
  double s2 = (q0 + q1) + (q2 + q3);

  // wave-64 shuffle tree
  for (int off = 32; off > 0; off >>= 1) {
    s1 += __shfl_down(s1, off, 64);
    s2 += __shfl_down(s2, off, 64);
  }

  __shared__ double sh1[4], sh2[4];
  int wave = tid >> 6, lane = tid & 63;
  if (lane == 0) { sh1[wave] = s1; sh2[wave] = s2; }
  __syncthreads();
  if (tid == 0) {
    double t1 = (sh1[0] + sh1[1]) + (sh1[2] + sh1[3]);
    double t2 = (sh2[0] + sh2[1]) + (sh2[2] + sh2[3]);
    part[gb] = make_double2(t1, t2);
  }
}

// One block, 16 waves; wave w = (imgi*8 + b). Group's 128 partials are
// contiguous at part[w*128 .. w*128+127] (8 c-planes x 16 chunks).
__global__ __launch_bounds__(1024) void moments_pass2(
    const double2* __restrict__ part, float* __restrict__ out) {
  int tid  = threadIdx.x;
  int w    = tid >> 6;          // 0..15
  int lane = tid & 63;
  int b    = w & 7;

  const double2 p0 = part[w * 128 + lane];
  const double2 p1 = part[w * 128 + 64 + lane];
  int c0 = lane >> 4;           // 0..3
  int c1 = c0 + 4;              // 4..7

  double s1 = p0.x + p1.x;
  double s2 = p0.y + p1.y;
  double d1 = (c0 == b ? p0.x : 0.0) + (c1 == b ? p1.x : 0.0);
  double d2 = (c0 == b ? p0.y : 0.0) + (c1 == b ? p1.y : 0.0);

  for (int off = 32; off > 0; off >>= 1) {
    s1 += __shfl_down(s1, off, 64);
    s2 += __shfl_down(s2, off, 64);
    d1 += __shfl_down(d1, off, 64);
    d2 += __shfl_down(d2, off, 64);
  }

  __shared__ double msh[16];
  if (lane == 0) {
    const double N    = (double)NCHW;      // 8388608
    const double Npix = (double)PLANE;     // 1048576
    const double denom = N * N;            // (C*H*W)^2, ORDER=2
    double mean = s1 / N;
    double var  = (s2 - s1 * s1 / N) / (N - 1.0);   // unbiased (ddof=1)
    double ssq  = d2 - 2.0 * mean * d1 + Npix * mean * mean;
    msh[w] = ssq / var / denom;
  }
  __syncthreads();
  if (tid == 0) {
    double m0 = 0.0, m1 = 0.0;
    for (int i = 0; i < 8; ++i)  m0 += msh[i];
    for (int i = 8; i < 16; ++i) m1 += msh[i];
    out[0] = (float)fabs(m0 - m1);
  }
}

extern "C" void kernel_launch(void* const* d_in, const int* in_sizes, int n_in,
                              void* d_out, int out_size, void* d_ws, size_t ws_size,
                              hipStream_t stream) {
  const float* img0 = (const float*)d_in[0];
  const float* img1 = (const float*)d_in[1];
  double2* part = (double2*)d_ws;   // 2048 * 16 B = 32 KiB, fully overwritten
  moments_pass1<<<NBLOCKS, THREADS, 0, stream>>>(img0, img1, part);
  moments_pass2<<<1, 1024, 0, stream>>>(part, (float*)d_out);
}